// Round 1
// baseline (172.627 us; speedup 1.0000x reference)
//
#include <hip/hip_runtime.h>
#include <hip/hip_bf16.h>
#include <math.h>

// AdditiveAttention: B=4, Q=512, K=512, H=256, all fp32.
// q = queries @ Wq^T ; k = keys @ Wk^T
// scores = sum_h tanh(q+k)*wv  -> softmax_k -> attn @ values
//
// tanh(x) = 1 - 2/(1+exp(2x)); sum_h wv*tanh = const - 2*sum_h wv*r,
// const drops out of softmax. Projections pre-scaled by 2*log2(e) so the
// inner loop is add/exp2/add/rcp/fma only.

#define B_ 4
#define Q_ 512
#define K_ 512
#define H_ 256

static constexpr float CEXP = 2.8853900817779268f; // 2*log2(e)
static constexpr float LOG2E = 1.4426950408889634f;

// ---------------------------------------------------------------------------
// proj_nt: C[m,n] = scale * sum_d A[m,d] * S[n,d]   (A: MxD, S: NxD, row-major)
// D = 256 fixed. 64x64 tile, 256 threads, 4x4 microtile, d-chunks of 16.
// LDS staged transposed (As[d][m]) so inner reads are float4 (ds_read_b128).
// ---------------------------------------------------------------------------
__global__ __launch_bounds__(256) void proj_nt(const float* __restrict__ A,
                                               const float* __restrict__ S,
                                               float* __restrict__ C,
                                               int ldc,
                                               long strideSz, long strideCz,
                                               float scale) {
    S += (long)blockIdx.z * strideSz;
    C += (long)blockIdx.z * strideCz;
    const int tile_m = blockIdx.y * 64;
    const int tile_n = blockIdx.x * 64;

    // row stride 68 floats: keeps float4 (16B) alignment, 68%32=4 bank skew
    __shared__ float As[16][68];
    __shared__ float Ss[16][68];

    const int tid = threadIdx.x;
    const int tx = tid & 15;        // 0..15 -> n
    const int ty = tid >> 4;        // 0..15 -> m
    const int ldr = tid >> 2;       // 0..63 row within tile (staging)
    const int ldd = (tid & 3) * 4;  // 0,4,8,12 d-offset (staging, float4)

    float acc[4][4] = {};

    for (int d0 = 0; d0 < H_; d0 += 16) {
        float4 av = *(const float4*)&A[(tile_m + ldr) * H_ + d0 + ldd];
        float4 sv = *(const float4*)&S[(tile_n + ldr) * H_ + d0 + ldd];
        __syncthreads();  // previous chunk's readers done
        As[ldd + 0][ldr] = av.x; As[ldd + 1][ldr] = av.y;
        As[ldd + 2][ldr] = av.z; As[ldd + 3][ldr] = av.w;
        Ss[ldd + 0][ldr] = sv.x; Ss[ldd + 1][ldr] = sv.y;
        Ss[ldd + 2][ldr] = sv.z; Ss[ldd + 3][ldr] = sv.w;
        __syncthreads();
#pragma unroll
        for (int dd = 0; dd < 16; ++dd) {
            float4 a4 = *(const float4*)&As[dd][ty * 4];
            float4 b4 = *(const float4*)&Ss[dd][tx * 4];
            float am[4] = {a4.x, a4.y, a4.z, a4.w};
            float bn[4] = {b4.x, b4.y, b4.z, b4.w};
#pragma unroll
            for (int i = 0; i < 4; ++i)
#pragma unroll
                for (int j = 0; j < 4; ++j)
                    acc[i][j] = fmaf(am[i], bn[j], acc[i][j]);
        }
    }

#pragma unroll
    for (int i = 0; i < 4; ++i)
#pragma unroll
        for (int j = 0; j < 4; ++j)
            C[(long)(tile_m + ty * 4 + i) * ldc + tile_n + tx * 4 + j] =
                scale * acc[i][j];
}

// ---------------------------------------------------------------------------
// attn_fused: one block per (b, 4 q-rows). 256 threads.
// Phase 1: scores (thread t owns k=t and k=t+256 for all 4 q rows)
// Phase 2: softmax per q row (wave w handles q=w)
// Phase 3: out = attn @ V (thread t = output dim h=t)
// ---------------------------------------------------------------------------
__global__ __launch_bounds__(256) void attn_fused(const float* __restrict__ qs,
                                                  const float* __restrict__ kst,
                                                  const float* __restrict__ values,
                                                  const float* __restrict__ wv,
                                                  float* __restrict__ out) {
    const int b = blockIdx.y;
    const int q0 = blockIdx.x * 4;
    const int t = threadIdx.x;

    __shared__ float sQ[4][H_];   // scaled q-projection rows
    __shared__ float sS[4][K_];   // scores -> attn
    __shared__ float wvs[H_];

#pragma unroll
    for (int i = 0; i < 4; ++i)
        sQ[i][t] = qs[((long)(b * Q_ + q0 + i)) * H_ + t];
    wvs[t] = wv[t];
    __syncthreads();

    float acc[4][2] = {};
    const float* kb = kst + (long)b * H_ * K_;

    for (int h = 0; h < H_; h += 4) {
        float4 wv4 = *(const float4*)&wvs[h];
        float4 q4[4];
#pragma unroll
        for (int qq = 0; qq < 4; ++qq) q4[qq] = *(const float4*)&sQ[qq][h];

#define UB(u, COMP)                                                         \
        {                                                                   \
            const float* kh = kb + (h + u) * K_ + t;                        \
            float k0 = kh[0];                                               \
            float k1 = kh[256];                                             \
            float wvh = wv4.COMP;                                           \
            _Pragma("unroll")                                               \
            for (int qq = 0; qq < 4; ++qq) {                                \
                float qh = q4[qq].COMP;                                     \
                float e0 = __builtin_amdgcn_exp2f(qh + k0);                 \
                acc[qq][0] = fmaf(wvh, __builtin_amdgcn_rcpf(1.0f + e0),    \
                                  acc[qq][0]);                              \
                float e1 = __builtin_amdgcn_exp2f(qh + k1);                 \
                acc[qq][1] = fmaf(wvh, __builtin_amdgcn_rcpf(1.0f + e1),    \
                                  acc[qq][1]);                              \
            }                                                               \
        }
        UB(0, x) UB(1, y) UB(2, z) UB(3, w)
#undef UB
    }

    // scores (up to softmax-invariant constant): s = -2 * acc
#pragma unroll
    for (int qq = 0; qq < 4; ++qq) {
        sS[qq][t] = -2.0f * acc[qq][0];
        sS[qq][t + 256] = -2.0f * acc[qq][1];
    }
    __syncthreads();

    // softmax: wave w -> q row w
    {
        const int lane = t & 63;
        const int q = t >> 6;
        float sv[8];
        float m = -INFINITY;
#pragma unroll
        for (int j = 0; j < 8; ++j) {
            sv[j] = sS[q][lane + 64 * j];
            m = fmaxf(m, sv[j]);
        }
#pragma unroll
        for (int off = 32; off >= 1; off >>= 1)
            m = fmaxf(m, __shfl_xor(m, off));
        float sum = 0.0f;
#pragma unroll
        for (int j = 0; j < 8; ++j) {
            sv[j] = __builtin_amdgcn_exp2f((sv[j] - m) * LOG2E);
            sum += sv[j];
        }
#pragma unroll
        for (int off = 32; off >= 1; off >>= 1)
            sum += __shfl_xor(sum, off);
        float rs = 1.0f / sum;
#pragma unroll
        for (int j = 0; j < 8; ++j) sS[q][lane + 64 * j] = sv[j] * rs;
    }
    __syncthreads();

    // attn @ V: thread t = h
    {
        float facc[4] = {0.f, 0.f, 0.f, 0.f};
        const float* vb = values + (long)b * K_ * H_ + t;
        for (int k = 0; k < K_; k += 4) {
            float4 a0 = *(const float4*)&sS[0][k];
            float4 a1 = *(const float4*)&sS[1][k];
            float4 a2 = *(const float4*)&sS[2][k];
            float4 a3 = *(const float4*)&sS[3][k];
            float v0 = vb[(k + 0) * H_];
            float v1 = vb[(k + 1) * H_];
            float v2 = vb[(k + 2) * H_];
            float v3 = vb[(k + 3) * H_];
            facc[0] = fmaf(a0.x, v0, fmaf(a0.y, v1, fmaf(a0.z, v2, fmaf(a0.w, v3, facc[0]))));
            facc[1] = fmaf(a1.x, v0, fmaf(a1.y, v1, fmaf(a1.z, v2, fmaf(a1.w, v3, facc[1]))));
            facc[2] = fmaf(a2.x, v0, fmaf(a2.y, v1, fmaf(a2.z, v2, fmaf(a2.w, v3, facc[2]))));
            facc[3] = fmaf(a3.x, v0, fmaf(a3.y, v1, fmaf(a3.z, v2, fmaf(a3.w, v3, facc[3]))));
        }
#pragma unroll
        for (int qq = 0; qq < 4; ++qq)
            out[((long)(b * Q_ + q0 + qq)) * H_ + t] = facc[qq];
    }
}

extern "C" void kernel_launch(void* const* d_in, const int* in_sizes, int n_in,
                              void* d_out, int out_size, void* d_ws, size_t ws_size,
                              hipStream_t stream) {
    const float* queries = (const float*)d_in[0];  // [B,Q,H]
    const float* keys    = (const float*)d_in[1];  // [B,K,H]
    const float* values  = (const float*)d_in[2];  // [B,K,H]
    const float* Wq      = (const float*)d_in[3];  // [H,H]
    const float* Wk      = (const float*)d_in[4];  // [H,H]
    const float* wv      = (const float*)d_in[5];  // [H]
    float* out = (float*)d_out;

    // workspace: qs [B*Q, H] (2 MB) then kst [B][H][K] (2 MB) = 4 MB total
    float* qs  = (float*)d_ws;
    float* kst = qs + (long)B_ * Q_ * H_;

    // q-projection: C[bq,h] = CEXP * sum_d queries[bq,d]*Wq[h,d]
    proj_nt<<<dim3(H_ / 64, (B_ * Q_) / 64, 1), 256, 0, stream>>>(
        queries, Wq, qs, H_, 0, 0, CEXP);

    // k-projection (transposed): kst[b][h][k] = CEXP * sum_d Wk[h,d]*keys[b,k,d]
    proj_nt<<<dim3(K_ / 64, H_ / 64, B_), 256, 0, stream>>>(
        Wk, keys, kst, K_, (long)K_ * H_, (long)H_ * K_, CEXP);

    // fused scores -> softmax -> attn@V
    attn_fused<<<dim3(Q_ / 4, B_), 256, 0, stream>>>(qs, kst, values, wv, out);
}

// Round 2
// 143.488 us; speedup vs baseline: 1.2031x; 1.2031x over previous
//
#include <hip/hip_runtime.h>
#include <hip/hip_bf16.h>
#include <math.h>

// AdditiveAttention: B=4, Q=512, K=512, H=256, fp32.
// scores[b,q,k] = sum_h wv_h * tanh(qp[b,q,h] + kp[b,k,h]) -> softmax_k -> @V
//
// tanh(x) = 1 - 2/(1+e^{2x}); the sum_h wv_h constant drops out of softmax, so
// s ~ -2*sum_h wv_h/(1+e^{2x}).  e^{2(q+k)} = e^{2q}*e^{2k}: exponentiate the
// projections ONCE (GEMM epilogue), so the O(B*Q*K*H) inner loop has no exp.
// 4 h-terms share one rcp: sum wv_i/t_i = N/(t0*t1*t2*t3) via 2-level combine.

#define B_ 4
#define Q_ 512
#define K_ 512
#define H_ 256

static constexpr float CEXP = 2.8853900817779268f; // 2*log2(e)
static constexpr float LOG2E = 1.4426950408889634f;

// ---------------------------------------------------------------------------
// proj_both: one launch, 256 blocks. blocks [0,128): qe = exp2(CEXP*(queries@Wq^T))
// blocks [128,256): ke[b][h][k] = exp2(CEXP * sum_d Wk[h,d]*keys[b,k,d]).
// 64x64 tile, 256 threads, 4x4 micro, d-chunks of 16, global prefetch pipeline.
// ---------------------------------------------------------------------------
__global__ __launch_bounds__(256, 4) void proj_both(
    const float* __restrict__ queries, const float* __restrict__ keys,
    const float* __restrict__ Wq, const float* __restrict__ Wk,
    float* __restrict__ qe, float* __restrict__ ke)
{
    const int bid = blockIdx.x;
    const float* A; const float* S; float* C; int ldc;
    if (bid < 128) {
        int mt = bid >> 2, nt = bid & 3;           // M=2048/64=32, N=256/64=4
        A = queries + mt * 64 * H_;
        S = Wq + nt * 64 * H_;
        C = qe + mt * 64 * H_ + nt * 64;
        ldc = H_;
    } else {
        int id = bid - 128;
        int b = id >> 5, mt = (id >> 3) & 3, nt = id & 7;  // m=h tiles:4, n=k tiles:8
        A = Wk + mt * 64 * H_;
        S = keys + (long)b * K_ * H_ + nt * 64 * H_;
        C = ke + (long)b * H_ * K_ + mt * 64 * K_ + nt * 64;
        ldc = K_;
    }

    // d-major transposed staging; stride 68: 16B-aligned rows, bank skew
    __shared__ float As[16][68];
    __shared__ float Ss[16][68];

    const int tid = threadIdx.x;
    const int tx = tid & 15;        // n-group -> n0 = tx*4
    const int ty = tid >> 4;        // m-group -> m0 = ty*4
    const int ldr = tid >> 2;       // 0..63 staging row
    const int ldd = (tid & 3) * 4;  // 0,4,8,12 staging d-offset

    const float* GA = A + ldr * H_ + ldd;
    const float* GS = S + ldr * H_ + ldd;

    float4 av = *(const float4*)GA;     // prefetch chunk 0
    float4 sv = *(const float4*)GS;

    float acc[4][4] = {};

    for (int d0 = 0; d0 < H_; d0 += 16) {
        As[ldd + 0][ldr] = av.x; As[ldd + 1][ldr] = av.y;
        As[ldd + 2][ldr] = av.z; As[ldd + 3][ldr] = av.w;
        Ss[ldd + 0][ldr] = sv.x; Ss[ldd + 1][ldr] = sv.y;
        Ss[ldd + 2][ldr] = sv.z; Ss[ldd + 3][ldr] = sv.w;
        __syncthreads();
        if (d0 + 16 < H_) {                 // prefetch next chunk (hidden by compute)
            av = *(const float4*)(GA + d0 + 16);
            sv = *(const float4*)(GS + d0 + 16);
        }
#pragma unroll
        for (int dd = 0; dd < 16; ++dd) {
            float4 a4 = *(const float4*)&As[dd][ty * 4];
            float4 b4 = *(const float4*)&Ss[dd][tx * 4];
            float am[4] = {a4.x, a4.y, a4.z, a4.w};
            float bn[4] = {b4.x, b4.y, b4.z, b4.w};
#pragma unroll
            for (int i = 0; i < 4; ++i)
#pragma unroll
                for (int j = 0; j < 4; ++j)
                    acc[i][j] = fmaf(am[i], bn[j], acc[i][j]);
        }
        __syncthreads();
    }

#pragma unroll
    for (int i = 0; i < 4; ++i) {
        float4 o;
        o.x = __builtin_amdgcn_exp2f(CEXP * acc[i][0]);
        o.y = __builtin_amdgcn_exp2f(CEXP * acc[i][1]);
        o.z = __builtin_amdgcn_exp2f(CEXP * acc[i][2]);
        o.w = __builtin_amdgcn_exp2f(CEXP * acc[i][3]);
        *(float4*)&C[(ty * 4 + i) * ldc + tx * 4] = o;
    }
}

// ---------------------------------------------------------------------------
// attn_fused: grid (Q/4, B), 512 threads (8 waves) -> 2 blocks/CU, 4 waves/SIMD.
// Phase 1: thread t = k; 4 q-rows; quad-rcp over h.
// Phase 2: softmax, wave w<4 -> row w.
// Phase 3: thread: 4 h (float4 V loads), 1 q, half of K; LDS cross-half reduce.
// ---------------------------------------------------------------------------
__global__ __launch_bounds__(512, 4) void attn_fused(
    const float* __restrict__ qe, const float* __restrict__ ke,
    const float* __restrict__ values, const float* __restrict__ wv,
    float* __restrict__ out)
{
    const int b = blockIdx.y;
    const int q0 = blockIdx.x * 4;
    const int t = threadIdx.x;

    __shared__ __align__(16) float sQ[4][H_];
    __shared__ __align__(16) float sS[4][K_];
    __shared__ __align__(16) float wvs[H_];

    {
        int row = t >> 7, col = (t & 127) * 2;
        *(float2*)&sQ[row][col] =
            *(const float2*)&qe[((long)(b * Q_ + q0 + row)) * H_ + col];
        if (t < H_) wvs[t] = wv[t];
    }
    __syncthreads();

    // ---- Phase 1: scores. thread t owns k = t.
    {
        const float* keb = ke + (long)b * H_ * K_ + t;
        float acc[4] = {0.f, 0.f, 0.f, 0.f};
#pragma unroll 2
        for (int h = 0; h < H_; h += 4) {
            float4 w4 = *(const float4*)&wvs[h];
            float k0 = keb[(h + 0) * K_];
            float k1 = keb[(h + 1) * K_];
            float k2 = keb[(h + 2) * K_];
            float k3 = keb[(h + 3) * K_];
#pragma unroll
            for (int q = 0; q < 4; ++q) {
                float4 e = *(const float4*)&sQ[q][h];
                float t0 = fmaf(e.x, k0, 1.0f);
                float t1 = fmaf(e.y, k1, 1.0f);
                float t2 = fmaf(e.z, k2, 1.0f);
                float t3 = fmaf(e.w, k3, 1.0f);
                float d01 = t0 * t1, d23 = t2 * t3;
                float n01 = fmaf(w4.x, t1, w4.y * t0);
                float n23 = fmaf(w4.z, t3, w4.w * t2);
                float num = fmaf(n01, d23, n23 * d01);
                float den = d01 * d23;
                acc[q] = fmaf(num, __builtin_amdgcn_rcpf(den), acc[q]);
            }
        }
#pragma unroll
        for (int q = 0; q < 4; ++q) sS[q][t] = -2.0f * acc[q];
    }
    __syncthreads();

    // ---- Phase 2: softmax, wave w (w<4) -> q row w
    if (t < 256) {
        const int lane = t & 63;
        const int q = t >> 6;
        float sv[8];
        float m = -INFINITY;
#pragma unroll
        for (int j = 0; j < 8; ++j) {
            sv[j] = sS[q][lane + 64 * j];
            m = fmaxf(m, sv[j]);
        }
#pragma unroll
        for (int off = 32; off >= 1; off >>= 1) m = fmaxf(m, __shfl_xor(m, off));
        float sum = 0.f;
#pragma unroll
        for (int j = 0; j < 8; ++j) {
            sv[j] = __builtin_amdgcn_exp2f((sv[j] - m) * LOG2E);
            sum += sv[j];
        }
#pragma unroll
        for (int off = 32; off >= 1; off >>= 1) sum += __shfl_xor(sum, off);
        float rs = 1.0f / sum;
#pragma unroll
        for (int j = 0; j < 8; ++j) sS[q][lane + 64 * j] = sv[j] * rs;
    }
    __syncthreads();

    // ---- Phase 3: attn @ V.
    {
        const int h4 = (t & 63) * 4;
        const int q = (t >> 6) & 3;
        const int khalf = t >> 8;
        const float* vb = values + (long)b * K_ * H_ + h4;
        float4 acc = {0.f, 0.f, 0.f, 0.f};
        const int kbeg = khalf * 256;
        for (int k = kbeg; k < kbeg + 256; k += 4) {
            float4 a = *(const float4*)&sS[q][k];           // wave-uniform broadcast
            float4 v0 = *(const float4*)&vb[(k + 0) * H_];  // coalesced 16B/lane
            float4 v1 = *(const float4*)&vb[(k + 1) * H_];
            float4 v2 = *(const float4*)&vb[(k + 2) * H_];
            float4 v3 = *(const float4*)&vb[(k + 3) * H_];
            acc.x = fmaf(a.x, v0.x, fmaf(a.y, v1.x, fmaf(a.z, v2.x, fmaf(a.w, v3.x, acc.x))));
            acc.y = fmaf(a.x, v0.y, fmaf(a.y, v1.y, fmaf(a.z, v2.y, fmaf(a.w, v3.y, acc.y))));
            acc.z = fmaf(a.x, v0.z, fmaf(a.y, v1.z, fmaf(a.z, v2.z, fmaf(a.w, v3.z, acc.z))));
            acc.w = fmaf(a.x, v0.w, fmaf(a.y, v1.w, fmaf(a.z, v2.w, fmaf(a.w, v3.w, acc.w))));
        }
        __syncthreads();   // all sS reads done before reuse as reduction buffer
        float4* sRed = reinterpret_cast<float4*>(&sS[0][0]);  // 256 * 16B = 4KB
        if (khalf == 1) sRed[t & 255] = acc;
        __syncthreads();
        if (khalf == 0) {
            float4 p = sRed[t];
            acc.x += p.x; acc.y += p.y; acc.z += p.z; acc.w += p.w;
            *(float4*)&out[((long)(b * Q_ + q0 + q)) * H_ + h4] = acc;
        }
    }
}

extern "C" void kernel_launch(void* const* d_in, const int* in_sizes, int n_in,
                              void* d_out, int out_size, void* d_ws, size_t ws_size,
                              hipStream_t stream) {
    const float* queries = (const float*)d_in[0];  // [B,Q,H]
    const float* keys    = (const float*)d_in[1];  // [B,K,H]
    const float* values  = (const float*)d_in[2];  // [B,K,H]
    const float* Wq      = (const float*)d_in[3];  // [H,H]
    const float* Wk      = (const float*)d_in[4];  // [H,H]
    const float* wv      = (const float*)d_in[5];  // [H]
    float* out = (float*)d_out;

    // workspace: qe [B*Q, H] (2 MB) then ke [B][H][K] (2 MB)
    float* qe = (float*)d_ws;
    float* ke = qe + (long)B_ * Q_ * H_;

    proj_both<<<256, 256, 0, stream>>>(queries, keys, Wq, Wk, qe, ke);
    attn_fused<<<dim3(Q_ / 4, B_), 512, 0, stream>>>(qe, ke, values, wv, out);
}

// Round 3
// 137.483 us; speedup vs baseline: 1.2556x; 1.0437x over previous
//
#include <hip/hip_runtime.h>
#include <hip/hip_bf16.h>
#include <math.h>

// AdditiveAttention: B=4, Q=512, K=512, H=256, fp32.
// scores[b,q,k] = sum_h wv_h * tanh(qp + kp) -> softmax_k -> @V
// tanh(x) = 1 - 2/(1+e^{2x}); sum_h wv_h drops out of softmax.
// e^{2(q+k)} = e^{2q} * e^{2k}: exponentiate projections once.
// 4 h-terms share one rcp: sum wv_i/t_i = num/(t0*t1*t2*t3).

#define B_ 4
#define Q_ 512
#define K_ 512
#define H_ 256

#define QE_ELEMS (B_ * Q_ * H_)           // 524288
#define KE_ELEMS (B_ * H_ * K_)           // 524288
#define HALF_ELEMS (QE_ELEMS + KE_ELEMS)  // 1048576 (one partial set)

static constexpr float CEXP = 2.8853900817779268f; // 2*log2(e)
static constexpr float LOG2E = 1.4426950408889634f;

// ---------------------------------------------------------------------------
// proj_partial: 512 blocks x 256 thr. Each block: one 64x64 output tile over
// HALF of the d-reduction (128). Partial sums to ws (no exp).
//   blocks [0,256):  qe partials  (tile, dhalf)
//   blocks [256,512): ke partials (tile, dhalf)   ke[b][h][k]
// Double-buffered LDS (d-major transposed), register prefetch, 1 barrier/chunk.
// ---------------------------------------------------------------------------
__global__ __launch_bounds__(256) void proj_partial(
    const float* __restrict__ queries, const float* __restrict__ keys,
    const float* __restrict__ Wq, const float* __restrict__ Wk,
    float* __restrict__ ws)
{
    const int bid = blockIdx.x;
    const float* A; const float* S; float* Cp; int ldc;
    if (bid < 256) {
        int dhalf = bid & 1;
        int tile = bid >> 1;                    // 128 tiles: 32 m x 4 n
        int mt = tile >> 2, nt = tile & 3;
        A = queries + (mt * 64) * H_ + dhalf * 128;
        S = Wq + (nt * 64) * H_ + dhalf * 128;
        Cp = ws + (long)dhalf * HALF_ELEMS + (mt * 64) * H_ + nt * 64;
        ldc = H_;
    } else {
        int id = bid - 256;
        int dhalf = id & 1;
        int tile = id >> 1;                     // 128: b(4) x mt(4) x nt(8)
        int b = tile >> 5, mt = (tile >> 3) & 3, nt = tile & 7;
        A = Wk + (mt * 64) * H_ + dhalf * 128;
        S = keys + ((long)b * K_ + nt * 64) * H_ + dhalf * 128;
        Cp = ws + (long)dhalf * HALF_ELEMS + QE_ELEMS +
             ((long)b * H_ + mt * 64) * K_ + nt * 64;
        ldc = K_;
    }

    // d-major transposed staging; stride 68: 16B rows, bank skew; double buffer
    __shared__ float As[2][16][68];
    __shared__ float Ss[2][16][68];

    const int tid = threadIdx.x;
    const int tx = tid & 15;         // n0 = tx*4
    const int ty = tid >> 4;         // m0 = ty*4
    const int ldr = tid >> 2;        // staging row 0..63
    const int ldd = (tid & 3) * 4;   // staging d-offset 0,4,8,12

    const float* GA = A + ldr * H_ + ldd;
    const float* GS = S + ldr * H_ + ldd;

    float4 av = *(const float4*)GA;
    float4 sv = *(const float4*)GS;
    As[0][ldd + 0][ldr] = av.x; As[0][ldd + 1][ldr] = av.y;
    As[0][ldd + 2][ldr] = av.z; As[0][ldd + 3][ldr] = av.w;
    Ss[0][ldd + 0][ldr] = sv.x; Ss[0][ldd + 1][ldr] = sv.y;
    Ss[0][ldd + 2][ldr] = sv.z; Ss[0][ldd + 3][ldr] = sv.w;

    float acc[4][4] = {};

#pragma unroll
    for (int c = 0; c < 8; ++c) {           // 8 chunks x 16 d = 128 d
        const int cur = c & 1;
        if (c < 7) {                        // prefetch next chunk to regs
            av = *(const float4*)(GA + (c + 1) * 16);
            sv = *(const float4*)(GS + (c + 1) * 16);
        }
        __syncthreads();                    // buf[cur] writes visible
#pragma unroll
        for (int dd = 0; dd < 16; ++dd) {
            float4 a4 = *(const float4*)&As[cur][dd][ty * 4];
            float4 b4 = *(const float4*)&Ss[cur][dd][tx * 4];
            float am[4] = {a4.x, a4.y, a4.z, a4.w};
            float bn[4] = {b4.x, b4.y, b4.z, b4.w};
#pragma unroll
            for (int i = 0; i < 4; ++i)
#pragma unroll
                for (int j = 0; j < 4; ++j)
                    acc[i][j] = fmaf(am[i], bn[j], acc[i][j]);
        }
        if (c < 7) {                        // fill other buffer (read 2 iters ago)
            const int nxt = cur ^ 1;
            As[nxt][ldd + 0][ldr] = av.x; As[nxt][ldd + 1][ldr] = av.y;
            As[nxt][ldd + 2][ldr] = av.z; As[nxt][ldd + 3][ldr] = av.w;
            Ss[nxt][ldd + 0][ldr] = sv.x; Ss[nxt][ldd + 1][ldr] = sv.y;
            Ss[nxt][ldd + 2][ldr] = sv.z; Ss[nxt][ldd + 3][ldr] = sv.w;
        }
    }

#pragma unroll
    for (int i = 0; i < 4; ++i) {
        float4 o = {acc[i][0], acc[i][1], acc[i][2], acc[i][3]};
        *(float4*)&Cp[(ty * 4 + i) * ldc + tx * 4] = o;
    }
}

// ---------------------------------------------------------------------------
// exp_combine: ws[i] = exp2(CEXP*(ws[i] + ws[i+HALF])) for i in [0, HALF).
// 1024 blocks x 256 thr, float4 each.
// ---------------------------------------------------------------------------
__global__ __launch_bounds__(256) void exp_combine(float* __restrict__ ws)
{
    const int i = blockIdx.x * 256 + threadIdx.x;     // 0..262143 (float4 idx)
    float4* w4 = (float4*)ws;
    float4 a = w4[i];
    float4 b = w4[i + HALF_ELEMS / 4];
    float4 o;
    o.x = __builtin_amdgcn_exp2f(CEXP * (a.x + b.x));
    o.y = __builtin_amdgcn_exp2f(CEXP * (a.y + b.y));
    o.z = __builtin_amdgcn_exp2f(CEXP * (a.z + b.z));
    o.w = __builtin_amdgcn_exp2f(CEXP * (a.w + b.w));
    w4[i] = o;
}

// ---------------------------------------------------------------------------
// attn_fused: grid (Q/4, B), 1024 threads (16 waves) -> 2 blocks/CU = 100% occ
// (needs VGPR<=64, hence __launch_bounds__(1024,8)).
// Phase 1: thread = (k, h-half); 4 q rows; quad-rcp; register prefetch.
//          h-halves combined via LDS partials.
// Phase 2: softmax, wave w<4 -> q row w.
// Phase 3: thread = (4 h, q, k-quarter); float4 V loads; LDS reduce.
// ---------------------------------------------------------------------------
__global__ __launch_bounds__(1024, 8) void attn_fused(
    const float* __restrict__ qe, const float* __restrict__ ke,
    const float* __restrict__ values, const float* __restrict__ wv,
    float* __restrict__ out)
{
    const int b = blockIdx.y;
    const int q0 = blockIdx.x * 4;
    const int t = threadIdx.x;

    // flat LDS: sQ[4][256] | wvs[256] | sS[4][512] | sP[4][512]  (21 KB)
    __shared__ __align__(16) float smem[4 * H_ + H_ + 4 * K_ + 4 * K_];
    float* sQ  = smem;               // [4][H_]
    float* wvs = smem + 4 * H_;      // [H_]
    float* sS  = smem + 5 * H_;      // [4][K_]
    float* sP  = smem + 5 * H_ + 4 * K_;  // [4][K_]

    // stage q-rows (exp'd) + wv
    sQ[t & 1023] = qe[((long)(b * Q_ + q0 + (t >> 8))) * H_ + (t & 255)];
    if (t < H_) wvs[t] = wv[t];
    __syncthreads();

    // ---- Phase 1: scores. thread = (k = t&511, h-half = t>>9)
    {
        const int k = t & 511;
        const int hh = t >> 9;
        const float* keb = ke + ((long)b * H_ + hh * 128) * K_ + k;

        float n0 = keb[0 * K_], n1 = keb[1 * K_], n2 = keb[2 * K_], n3 = keb[3 * K_];
        float acc[4] = {0.f, 0.f, 0.f, 0.f};

#pragma unroll 2
        for (int hl = 0; hl < 128; hl += 4) {
            float k0 = n0, k1 = n1, k2 = n2, k3 = n3;
            if (hl < 124) {                   // prefetch next h-group
                const float* p = keb + (hl + 4) * K_;
                n0 = p[0]; n1 = p[K_]; n2 = p[2 * K_]; n3 = p[3 * K_];
            }
            const int h = hh * 128 + hl;
            float4 w4 = *(const float4*)&wvs[h];
#pragma unroll
            for (int q = 0; q < 4; ++q) {
                float4 e = *(const float4*)&sQ[q * H_ + h];
                float t0 = fmaf(e.x, k0, 1.0f);
                float t1 = fmaf(e.y, k1, 1.0f);
                float t2 = fmaf(e.z, k2, 1.0f);
                float t3 = fmaf(e.w, k3, 1.0f);
                float d01 = t0 * t1, d23 = t2 * t3;
                float n01 = fmaf(w4.x, t1, w4.y * t0);
                float n23 = fmaf(w4.z, t3, w4.w * t2);
                float num = fmaf(n01, d23, n23 * d01);
                acc[q] = fmaf(num, __builtin_amdgcn_rcpf(d01 * d23), acc[q]);
            }
        }

        if (hh == 1) {
#pragma unroll
            for (int q = 0; q < 4; ++q) sP[q * K_ + k] = acc[q];
        }
        __syncthreads();
        if (hh == 0) {
#pragma unroll
            for (int q = 0; q < 4; ++q)
                sS[q * K_ + k] = -2.0f * (acc[q] + sP[q * K_ + k]);
        }
    }
    __syncthreads();

    // ---- Phase 2: softmax, wave w (w<4) -> q row w
    if (t < 256) {
        const int lane = t & 63;
        const int q = t >> 6;
        float sv[8];
        float m = -INFINITY;
#pragma unroll
        for (int j = 0; j < 8; ++j) {
            sv[j] = sS[q * K_ + lane + 64 * j];
            m = fmaxf(m, sv[j]);
        }
#pragma unroll
        for (int off = 32; off >= 1; off >>= 1) m = fmaxf(m, __shfl_xor(m, off));
        float sum = 0.f;
#pragma unroll
        for (int j = 0; j < 8; ++j) {
            sv[j] = __builtin_amdgcn_exp2f((sv[j] - m) * LOG2E);
            sum += sv[j];
        }
#pragma unroll
        for (int off = 32; off >= 1; off >>= 1) sum += __shfl_xor(sum, off);
        float rs = 1.0f / sum;
#pragma unroll
        for (int j = 0; j < 8; ++j) sS[q * K_ + lane + 64 * j] = sv[j] * rs;
    }
    __syncthreads();

    // ---- Phase 3: attn @ V. thread = (h4 = (t&63)*4, q = (t>>6)&3, kq = t>>8)
    {
        const int lane = t & 63;
        const int h4 = lane * 4;
        const int q = (t >> 6) & 3;
        const int kq = t >> 8;                 // k-quarter, 128 k each
        const float* vb = values + (long)b * K_ * H_ + h4;
        const float* sSq = sS + q * K_;
        float4 acc = {0.f, 0.f, 0.f, 0.f};
        const int kbeg = kq * 128;
        for (int k = kbeg; k < kbeg + 128; k += 4) {
            float4 a = *(const float4*)&sSq[k];             // uniform broadcast
            float4 v0 = *(const float4*)&vb[(k + 0) * H_];  // 1KB/wave coalesced
            float4 v1 = *(const float4*)&vb[(k + 1) * H_];
            float4 v2 = *(const float4*)&vb[(k + 2) * H_];
            float4 v3 = *(const float4*)&vb[(k + 3) * H_];
            acc.x = fmaf(a.x, v0.x, fmaf(a.y, v1.x, fmaf(a.z, v2.x, fmaf(a.w, v3.x, acc.x))));
            acc.y = fmaf(a.x, v0.y, fmaf(a.y, v1.y, fmaf(a.z, v2.y, fmaf(a.w, v3.y, acc.y))));
            acc.z = fmaf(a.x, v0.z, fmaf(a.y, v1.z, fmaf(a.z, v2.z, fmaf(a.w, v3.z, acc.z))));
            acc.w = fmaf(a.x, v0.w, fmaf(a.y, v1.w, fmaf(a.z, v2.w, fmaf(a.w, v3.w, acc.w))));
        }
        __syncthreads();   // all sS reads done; reuse sS+sP as reduction buffer
        float4* sRed = (float4*)sS;                         // 1024 float4 slots
        if (kq) sRed[(kq - 1) * 256 + q * 64 + lane] = acc;
        __syncthreads();
        if (kq == 0) {
            float4 p1 = sRed[q * 64 + lane];
            float4 p2 = sRed[256 + q * 64 + lane];
            float4 p3 = sRed[512 + q * 64 + lane];
            acc.x += p1.x + p2.x + p3.x;
            acc.y += p1.y + p2.y + p3.y;
            acc.z += p1.z + p2.z + p3.z;
            acc.w += p1.w + p2.w + p3.w;
            *(float4*)&out[((long)(b * Q_ + q0 + q)) * H_ + h4] = acc;
        }
    }
}

extern "C" void kernel_launch(void* const* d_in, const int* in_sizes, int n_in,
                              void* d_out, int out_size, void* d_ws, size_t ws_size,
                              hipStream_t stream) {
    const float* queries = (const float*)d_in[0];  // [B,Q,H]
    const float* keys    = (const float*)d_in[1];  // [B,K,H]
    const float* values  = (const float*)d_in[2];  // [B,K,H]
    const float* Wq      = (const float*)d_in[3];  // [H,H]
    const float* Wk      = (const float*)d_in[4];  // [H,H]
    const float* wv      = (const float*)d_in[5];  // [H]
    float* out = (float*)d_out;

    // ws layout (fp32): [qe 524288][ke 524288][qeP1 524288][keP1 524288] = 8MB
    float* ws = (float*)d_ws;
    float* qe = ws;
    float* ke = ws + QE_ELEMS;

    proj_partial<<<512, 256, 0, stream>>>(queries, keys, Wq, Wk, ws);
    exp_combine<<<HALF_ELEMS / 1024, 256, 0, stream>>>(ws);
    attn_fused<<<dim3(Q_ / 4, B_), 1024, 0, stream>>>(qe, ke, values, wv, out);
}